// Round 1
// 118.069 us; speedup vs baseline: 1.0470x; 1.0470x over previous
//
#include <hip/hip_runtime.h>
#include <stdint.h>
#include <math.h>

typedef __attribute__((ext_vector_type(8))) short short8;
typedef __attribute__((ext_vector_type(4))) float floatx4;

// ---------------- LDS layout (51200 B) ----------------
#define L_HF    0        // 32768: W1 B-frags, then h B-frags: [ct(8)][ks(4)][lane(64)] x 16B
#define L_SRC   32768    // 4096 : att_src [8][128] f32 (pre-scaled by log2e)
#define L_DST   36864    // 4096 : att_dst [8][128] f32 (pre-scaled by log2e)
#define L_MASK  40960    // 2048 : mask bits [128 rows][16 B]
#define L_H2P   43008    // 8192 : layer-2 partials float2[8 heads][128 nodes]
#define L_SIZE  51200

union F8 { short8 s8; uint32_t u[4]; };

#if __has_builtin(__builtin_amdgcn_exp2f)
#define EXP2F __builtin_amdgcn_exp2f
#else
#define EXP2F exp2f
#endif
#define LOG2E  1.4426950408889634f
#define LOG2E2 2.8853900817779268f

__device__ __forceinline__ uint32_t packbf(float a, float b){
  uint32_t ua = __float_as_uint(a), ub = __float_as_uint(b);
  uint32_t ra = (ua + 0x7fffu + ((ua>>16)&1u)) >> 16;   // RNE bf16
  uint32_t rb = (ub + 0x7fffu + ((ub>>16)&1u)) >> 16;
  return ra | (rb<<16);
}
// truncation pack (1 inst): low16 = hi16(a), high16 = hi16(b)
__device__ __forceinline__ uint32_t packbf_t(float a, float b){
  return __builtin_amdgcn_perm(__float_as_uint(b), __float_as_uint(a), 0x07060302u);
}
__device__ __forceinline__ float fast_tanh(float x){
  float e = EXP2F(LOG2E2*x);                 // e^(2x)
  return fmaf(-2.f, __builtin_amdgcn_rcpf(e + 1.f), 1.f);
}
// masked exp2: returns exp2(l) if bit jj of mb set, else 0 (sign-extend+and).
__device__ __forceinline__ float mexp2(float l, uint32_t mb, int jj){
  float e = EXP2F(l);
  int sm = ((int)(mb << (31-jj))) >> 31;
  return __int_as_float(__float_as_int(e) & sm);
}
// sum over the 16-lane DPP row via row_ror — result valid in ALL lanes. Pure VALU.
__device__ __forceinline__ float red16(float x){
  x += __int_as_float(__builtin_amdgcn_update_dpp(0, __float_as_int(x), 0x128, 0xf, 0xf, true)); // row_ror:8
  x += __int_as_float(__builtin_amdgcn_update_dpp(0, __float_as_int(x), 0x124, 0xf, 0xf, true)); // row_ror:4
  x += __int_as_float(__builtin_amdgcn_update_dpp(0, __float_as_int(x), 0x122, 0xf, 0xf, true)); // row_ror:2
  x += __int_as_float(__builtin_amdgcn_update_dpp(0, __float_as_int(x), 0x121, 0xf, 0xf, true)); // row_ror:1
  return x;
}

// ---- prep: adjacency (b,n,n) int32 -> per-row 128-bit masks (dedup across s) ----
// Also zeroes the output buffer (atomicAdd target of gat_fused).
__global__ void mask_build(const int* __restrict__ adj, uint32_t* __restrict__ mask_ws,
                           float* __restrict__ out) {
  const int t = threadIdx.x;
  if (blockIdx.x == 0 && t < 256) out[t] = 0.f;
  const int row = blockIdx.x*4 + (t>>6);     // 4 waves/block, one row per wave
  const int lane = t & 63;
  const int* ar = adj + (size_t)row*128;
  uint64_t m0 = __ballot(ar[lane] != 0);
  uint64_t m1 = __ballot(ar[64+lane] != 0);
  if (lane == 0) {
    ((uint4*)mask_ws)[row] = make_uint4((uint32_t)m0, (uint32_t)(m0>>32),
                                        (uint32_t)m1, (uint32_t)(m1>>32));
  }
}

// ---- fully fused GAT: one block per (s, b), 8 waves, all 8 heads in-block ----
// Includes the layer-2 ego-row softmax + log_softmax; mean over S via atomicAdd.
__global__ __launch_bounds__(512,4) void gat_fused(
    const float* __restrict__ x,  const float* __restrict__ emb,
    const float* __restrict__ w1,
    const float* __restrict__ a_src1, const float* __restrict__ a_dst1,
    const float* __restrict__ b1, const float* __restrict__ w2,
    const float* __restrict__ a_src2, const float* __restrict__ a_dst2,
    const float* __restrict__ b2,
    const uint32_t* __restrict__ mask_ws, float* __restrict__ out)
{
  __shared__ __align__(16) char smem[L_SIZE];
  char*     hf    = smem + L_HF;
  uint32_t* hf_u  = (uint32_t*)(smem + L_HF);
  float*    src_l = (float*)(smem + L_SRC);
  float*    dst_l = (float*)(smem + L_DST);
  uint32_t* mask_l= (uint32_t*)(smem + L_MASK);
  const uint4* mask4 = (const uint4*)(smem + L_MASK);
  float2*   h2p   = (float2*)(smem + L_H2P);

  const int t    = threadIdx.x;
  const int blk  = blockIdx.x;
  const int s    = blk >> 7;
  const int bb   = blk & 127;
  const int lane = t & 63, w = t >> 6;
  const int of = lane & 15, kg = lane >> 4;

  // stage pre-packed mask rows (512 u32)
  mask_l[t] = mask_ws[(size_t)bb*512 + t];

  // ---------- Phase 0a: A-frags direct from global (rows w*16+of) ----------
  const int arow = w*16 + of;
  const float* xrow = x   + ((size_t)bb*128 + arow)*64;
  const float* erow = emb + ((size_t)bb*128 + arow)*64;
  short8 af[4];
  #pragma unroll
  for (int ks=0; ks<4; ++ks){
    int k = ks*32 + kg*8;
    const float* p = (k<64) ? (xrow+k) : (erow + (k-64));
    float4 f0 = *(const float4*)p, f1 = *(const float4*)(p+4);
    F8 fr;
    fr.u[0]=packbf_t(f0.x,f0.y); fr.u[1]=packbf_t(f0.z,f0.w);
    fr.u[2]=packbf_t(f1.x,f1.y); fr.u[3]=packbf_t(f1.z,f1.w);
    af[ks]=fr.s8;
  }

  // ---------- Phase 0b: stage ALL 8 heads of W1 as bf16 B-frags (32 KB) ----------
  {
    const float* w1s = w1 + (size_t)s*16384;   // 8 heads x 128 x 16
    #pragma unroll
    for (int r=0; r<4; ++r){
      int q = t + r*512;                       // 0..2047 = (ct*4+ks)*64 + qlane
      int ql = q & 63, ks = (q>>6)&3, ct = q>>8;
      const float* wp = w1s + ct*2048 + (ks*32 + (ql>>4)*8)*16 + (ql&15);
      F8 fr;
      fr.u[0]=packbf_t(wp[0],  wp[16]);
      fr.u[1]=packbf_t(wp[32], wp[48]);
      fr.u[2]=packbf_t(wp[64], wp[80]);
      fr.u[3]=packbf_t(wp[96], wp[112]);
      *(short8*)(hf + ((ct*4+ks)*64 + ql)*16) = fr.s8;
    }
  }
  __syncthreads();

  // ---------- Phase 1: h = x0 @ W1 via MFMA (8 heads) ----------
  floatx4 acc[8];
  #pragma unroll
  for (int ct=0; ct<8; ++ct) acc[ct]=(floatx4){0.f,0.f,0.f,0.f};
  #pragma unroll
  for (int ct=0; ct<8; ++ct)
    #pragma unroll
    for (int ks=0; ks<4; ++ks){
      short8 bfr = *(const short8*)(hf + ((ct*4+ks)*64 + lane)*16);
      acc[ct] = __builtin_amdgcn_mfma_f32_16x16x32_bf16(af[ks], bfr, acc[ct], 0,0,0);
    }
  __syncthreads();                            // all W1-frag reads done before h overwrite

  // epilogue: tanh -> att partials (x log2e) via DPP row-reduce; h -> LDS in B-frag order
  const int ks_h = w>>1, kgp = (w&1)*2 + (kg>>1), vv = (kg&1)*2;
  #pragma unroll
  for (int ct=0; ct<8; ++ct){
    float asv = a_src1[s*128 + ct*16 + of] * LOG2E;
    float adv = a_dst1[s*128 + ct*16 + of] * LOG2E;
    float ps[4], pd[4];
    #pragma unroll
    for (int r=0; r<4; ++r){
      float th = fast_tanh(acc[ct][r]);
      ps[r] = red16(th*asv); pd[r] = red16(th*adv);
    }
    if (of==0){
      #pragma unroll
      for (int r=0; r<4; ++r){
        int i = w*16 + kg*4 + r;
        src_l[ct*128+i]=ps[r]; dst_l[ct*128+i]=pd[r];
      }
    }
    uint32_t p0 = packbf(acc[ct][0], acc[ct][1]);
    uint32_t p1 = packbf(acc[ct][2], acc[ct][3]);
    uint32_t* dsth = hf_u + ((ct*4+ks_h)*64 + kgp*16 + of)*4 + vv;
    *(uint2*)dsth = make_uint2(p0, p1);
  }
  __syncthreads();

  // ---------- Phase 2: softmax(lrelu(src+dst)) @ h, fused elu + W2 dot ----------
  // One wave per head; paired row-tiles; z via MFMA-with-ones.
  const int hd = w;                           // head for this wave
  float b1v  = b1[of];
  float w2c0 = w2[s*256 + (hd*16+of)*2 + 0];
  float w2c1 = w2[s*256 + (hd*16+of)*2 + 1];
  F8 onesf;                                   // bf16 1.0 x8
  onesf.u[0]=0x3F803F80u; onesf.u[1]=0x3F803F80u;
  onesf.u[2]=0x3F803F80u; onesf.u[3]=0x3F803F80u;

  #pragma unroll 2
  for (int pp=0; pp<4; ++pp){
    const int rt0 = pp*2, rt1 = rt0 + 1;
    const int im0 = rt0*16 + of, im1 = rt1*16 + of;
    float srcv0 = src_l[hd*128 + im0];
    float srcv1 = src_l[hd*128 + im1];
    uint4 mrow0 = mask4[im0];
    uint4 mrow1 = mask4[im1];
    floatx4 acc20 = (floatx4){0.f,0.f,0.f,0.f};
    floatx4 acc21 = (floatx4){0.f,0.f,0.f,0.f};
    floatx4 accz0 = (floatx4){0.f,0.f,0.f,0.f};
    floatx4 accz1 = (floatx4){0.f,0.f,0.f,0.f};
    #pragma unroll
    for (int ks=0; ks<4; ++ks){
      const float* dp = dst_l + hd*128 + ks*32 + kg*8;
      float4 d0 = *(const float4*)dp, d1 = *(const float4*)(dp+4);
      short8 hbk = *(const short8*)(hf + ((hd*4+ks)*64 + lane)*16);
      uint32_t mw0 = (ks==0)?mrow0.x:(ks==1)?mrow0.y:(ks==2)?mrow0.z:mrow0.w;
      uint32_t mw1 = (ks==0)?mrow1.x:(ks==1)?mrow1.y:(ks==2)?mrow1.z:mrow1.w;
      uint32_t mb0 = mw0 >> (kg*8);
      uint32_t mb1 = mw1 >> (kg*8);
      float dj[8] = {d0.x,d0.y,d0.z,d0.w,d1.x,d1.y,d1.z,d1.w};
      F8 fr0, fr1;
      #pragma unroll
      for (int jp=0; jp<4; ++jp){
        const int j0 = 2*jp, j1 = 2*jp+1;
        float ta0 = srcv0 + dj[j0], ta1 = srcv0 + dj[j1];
        float tb0 = srcv1 + dj[j0], tb1 = srcv1 + dj[j1];
        float la0 = fmaxf(ta0, 0.2f*ta0), la1 = fmaxf(ta1, 0.2f*ta1);
        float lb0 = fmaxf(tb0, 0.2f*tb0), lb1 = fmaxf(tb1, 0.2f*tb1);
        float ea0 = mexp2(la0, mb0, j0), ea1 = mexp2(la1, mb0, j1);
        float eb0 = mexp2(lb0, mb1, j0), eb1 = mexp2(lb1, mb1, j1);
        fr0.u[jp] = packbf_t(ea0, ea1);
        fr1.u[jp] = packbf_t(eb0, eb1);
      }
      acc20 = __builtin_amdgcn_mfma_f32_16x16x32_bf16(fr0.s8, hbk,      acc20, 0,0,0);
      accz0 = __builtin_amdgcn_mfma_f32_16x16x32_bf16(fr0.s8, onesf.s8, accz0, 0,0,0);
      acc21 = __builtin_amdgcn_mfma_f32_16x16x32_bf16(fr1.s8, hbk,      acc21, 0,0,0);
      accz1 = __builtin_amdgcn_mfma_f32_16x16x32_bf16(fr1.s8, onesf.s8, accz1, 0,0,0);
    }
    #pragma unroll
    for (int pr=0; pr<2; ++pr){
      const int rt = pr ? rt1 : rt0;
      floatx4 a2 = pr ? acc21 : acc20;
      floatx4 az = pr ? accz1 : accz0;
      float pc0[4], pc1[4];
      #pragma unroll
      for (int r=0; r<4; ++r){
        float zi = __builtin_amdgcn_rcpf(az[r]);    // z for row kg*4+r, in-slot
        float o  = fmaf(a2[r], zi, b1v);
        float oe = (o>0.f) ? o : (__expf(o)-1.f);   // elu
        pc0[r] = red16(oe*w2c0);
        pc1[r] = red16(oe*w2c1);
      }
      if (of==0){
        #pragma unroll
        for (int r=0; r<4; ++r){
          int i = rt*16 + kg*4 + r;
          h2p[hd*128 + i] = make_float2(pc0[r], pc1[r]);
        }
      }
    }
  }
  __syncthreads();

  // ---------- in-block layer-2 tail: ego-row softmax + log_softmax ----------
  // hv[j][c] = sum over 8 heads of h2p; one wave handles all 128 nodes (2 j per lane).
  if (w == 0){
    float hv[2][2];
    #pragma unroll
    for (int jj=0; jj<2; ++jj){
      const int j = lane + jj*64;
      float s0 = 0.f, s1 = 0.f;
      #pragma unroll
      for (int h2i=0; h2i<8; ++h2i){
        float2 p = h2p[h2i*128 + j];
        s0 += p.x; s1 += p.y;
      }
      hv[jj][0] = s0; hv[jj][1] = s1;
    }
    const float as0 = a_src2[s*2+0], as1 = a_src2[s*2+1];
    const float ad0 = a_dst2[s*2+0], ad1 = a_dst2[s*2+1];
    float ps1v = 0.f, pd[2];
    #pragma unroll
    for (int jj=0; jj<2; ++jj){
      float th0 = fast_tanh(hv[jj][0]);
      float th1 = fast_tanh(hv[jj][1]);
      float psj = th0*as0 + th1*as1;
      pd[jj]    = th0*ad0 + th1*ad1;
      if (jj==1) ps1v = psj;
    }
    const float srcE = __shfl(ps1v, 63);       // ego node j=127
    const uint32_t mwA = mask_l[127*4 + (lane>>5)];
    const uint32_t mwB = mask_l[127*4 + 2 + (lane>>5)];
    const int bitpos = lane & 31;
    float v[2];
    #pragma unroll
    for (int jj=0; jj<2; ++jj){
      float t0 = srcE + pd[jj];
      float lg = fmaxf(t0, 0.2f*t0);
      uint32_t mb = jj ? mwB : mwA;
      v[jj] = ((mb >> bitpos) & 1u) ? lg : -1e9f;
    }
    float M = fmaxf(v[0], v[1]);
    #pragma unroll
    for (int off=32; off>=1; off>>=1) M = fmaxf(M, __shfl_xor(M, off));
    float e0 = __expf(v[0]-M), e1 = __expf(v[1]-M);
    float Z  = e0 + e1;
    float S0 = e0*hv[0][0] + e1*hv[1][0];
    float S1 = e0*hv[0][1] + e1*hv[1][1];
    #pragma unroll
    for (int off=32; off>=1; off>>=1){
      Z  += __shfl_xor(Z,  off);
      S0 += __shfl_xor(S0, off);
      S1 += __shfl_xor(S1, off);
    }
    if (lane == 0){
      float o0 = S0/Z + b2[0];
      float o1 = S1/Z + b2[1];
      float mm = fmaxf(o0,o1);
      float lse = mm + logf(__expf(o0-mm)+__expf(o1-mm));
      atomicAdd(out + bb*2 + 0, 0.25f*(o0 - lse));
      atomicAdd(out + bb*2 + 1, 0.25f*(o1 - lse));
    }
  }
}

extern "C" void kernel_launch(void* const* d_in, const int* in_sizes, int n_in,
                              void* d_out, int out_size, void* d_ws, size_t ws_size,
                              hipStream_t stream) {
  const float* x      = (const float*)d_in[0];
  const float* emb    = (const float*)d_in[1];
  const int*   adj    = (const int*)d_in[2];
  const float* w1     = (const float*)d_in[3];
  const float* a_src1 = (const float*)d_in[4];
  const float* a_dst1 = (const float*)d_in[5];
  const float* b1     = (const float*)d_in[6];
  const float* w2     = (const float*)d_in[7];
  const float* a_src2 = (const float*)d_in[8];
  const float* a_dst2 = (const float*)d_in[9];
  const float* b2     = (const float*)d_in[10];

  uint32_t* mask_ws = (uint32_t*)d_ws;   // 256 KB: 128 bb x 512 u32

  mask_build<<<dim3(4096), dim3(256), 0, stream>>>(adj, mask_ws, (float*)d_out);
  gat_fused<<<dim3(512), dim3(512), 0, stream>>>(x, emb, w1, a_src1, a_dst1, b1,
                                                 w2, a_src2, a_dst2, b2,
                                                 mask_ws, (float*)d_out);
}

// Round 2
// 116.848 us; speedup vs baseline: 1.0580x; 1.0104x over previous
//
#include <hip/hip_runtime.h>
#include <stdint.h>
#include <math.h>

typedef __attribute__((ext_vector_type(8))) short short8;
typedef __attribute__((ext_vector_type(4))) float floatx4;

// ---------------- LDS layout (51200 B) ----------------
#define L_HF    0        // 32768: W1 B-frags, then h B-frags: [ct(8)][ks(4)][lane(64)] x 16B
#define L_SRC   32768    // 4096 : att_src [8][128] f32 (pre-scaled by log2e)
#define L_DST   36864    // 4096 : att_dst [8][128] f32 (pre-scaled by log2e)
#define L_MASK  40960    // 2048 : mask bits [128 rows][16 B]
#define L_H2P   43008    // 8192 : layer-2 partials float2[8 heads][128 nodes]
#define L_SIZE  51200

// ---------------- workspace layout ----------------
#define WS_MASK   0              // 256 KB : 128 bb x 512 u32
#define WS_W1P    262144         // 128 KB : 4 s x 2048 lines x 16 B (bf16 B-frags)
#define WS_XP     393216         // 4 MB   : 128 bb x 8 w x 4 ks x 64 lane x 16 B (bf16 A-frags)

union F8 { short8 s8; uint32_t u[4]; };

#if __has_builtin(__builtin_amdgcn_exp2f)
#define EXP2F __builtin_amdgcn_exp2f
#else
#define EXP2F exp2f
#endif
#define LOG2E  1.4426950408889634f
#define LOG2E2 2.8853900817779268f

__device__ __forceinline__ uint32_t packbf(float a, float b){
  uint32_t ua = __float_as_uint(a), ub = __float_as_uint(b);
  uint32_t ra = (ua + 0x7fffu + ((ua>>16)&1u)) >> 16;   // RNE bf16
  uint32_t rb = (ub + 0x7fffu + ((ub>>16)&1u)) >> 16;
  return ra | (rb<<16);
}
// truncation pack (1 inst): low16 = hi16(a), high16 = hi16(b)
__device__ __forceinline__ uint32_t packbf_t(float a, float b){
  return __builtin_amdgcn_perm(__float_as_uint(b), __float_as_uint(a), 0x07060302u);
}
__device__ __forceinline__ float fast_tanh(float x){
  float e = EXP2F(LOG2E2*x);                 // e^(2x)
  return fmaf(-2.f, __builtin_amdgcn_rcpf(e + 1.f), 1.f);
}
// masked exp2: returns exp2(l) if bit jj of mb set, else 0 (sign-extend+and).
__device__ __forceinline__ float mexp2(float l, uint32_t mb, int jj){
  float e = EXP2F(l);
  int sm = ((int)(mb << (31-jj))) >> 31;
  return __int_as_float(__float_as_int(e) & sm);
}
// sum over the 16-lane DPP row via row_ror — result valid in ALL lanes. Pure VALU.
__device__ __forceinline__ float red16(float x){
  x += __int_as_float(__builtin_amdgcn_update_dpp(0, __float_as_int(x), 0x128, 0xf, 0xf, true)); // row_ror:8
  x += __int_as_float(__builtin_amdgcn_update_dpp(0, __float_as_int(x), 0x124, 0xf, 0xf, true)); // row_ror:4
  x += __int_as_float(__builtin_amdgcn_update_dpp(0, __float_as_int(x), 0x122, 0xf, 0xf, true)); // row_ror:2
  x += __int_as_float(__builtin_amdgcn_update_dpp(0, __float_as_int(x), 0x121, 0xf, 0xf, true)); // row_ror:1
  return x;
}

// ---- prep: masks + bf16 pre-pack of W1 and x0 (dedup across s/bb) + out zero ----
__global__ __launch_bounds__(256) void prep(
    const int* __restrict__ adj, const float* __restrict__ x,
    const float* __restrict__ emb, const float* __restrict__ w1,
    uint32_t* __restrict__ mask_ws, char* __restrict__ w1pack,
    char* __restrict__ xpack, float* __restrict__ out)
{
  const int t = threadIdx.x, blk = blockIdx.x;
  const int tid = blk*256 + t;
  if (tid < 256) out[tid] = 0.f;            // atomicAdd target of gat_fused

  // --- adjacency -> per-row 128-bit masks: 16384 rows, 8 rows per wave ---
  const int lane = t & 63;
  const int wg = tid >> 6;                  // global wave id 0..2047
  #pragma unroll
  for (int i=0;i<8;++i){
    const int row = wg*8 + i;
    const int* ar = adj + (size_t)row*128;
    uint64_t m0 = __ballot(ar[lane] != 0);
    uint64_t m1 = __ballot(ar[64+lane] != 0);
    if (lane == 0)
      ((uint4*)mask_ws)[row] = make_uint4((uint32_t)m0, (uint32_t)(m0>>32),
                                          (uint32_t)m1, (uint32_t)(m1>>32));
  }

  // --- W1 -> bf16 B-frag lines: [s][L(2048)] x 16B, L=(ct*4+ks)*64+ql ---
  if (tid < 8192){
    const int s = tid>>11, L = tid & 2047;
    const int ct = L>>8, ks = (L>>6)&3, ql = L&63;
    const float* wp = w1 + (size_t)s*16384 + ct*2048 + (ks*32 + (ql>>4)*8)*16 + (ql&15);
    F8 fr;
    fr.u[0]=packbf_t(wp[0],  wp[16]);
    fr.u[1]=packbf_t(wp[32], wp[48]);
    fr.u[2]=packbf_t(wp[64], wp[80]);
    fr.u[3]=packbf_t(wp[96], wp[112]);
    *(short8*)(w1pack + (size_t)tid*16) = fr.s8;
  }

  // --- x0=concat(x,emb) -> bf16 A-frag lines: [bb][w][ks][lane] x 16B ---
  #pragma unroll
  for (int rr=0; rr<2; ++rr){
    const int X = tid + rr*131072;          // 0..262143
    const int l9 = X & 63, ks = (X>>6)&3, wv = (X>>8)&7, bb = X>>11;
    const int row = wv*16 + (l9&15), k = ks*32 + (l9>>4)*8;
    const float* p = (k<64) ? (x   + ((size_t)bb*128+row)*64 + k)
                            : (emb + ((size_t)bb*128+row)*64 + (k-64));
    float4 f0 = *(const float4*)p, f1 = *(const float4*)(p+4);
    F8 fr;
    fr.u[0]=packbf_t(f0.x,f0.y); fr.u[1]=packbf_t(f0.z,f0.w);
    fr.u[2]=packbf_t(f1.x,f1.y); fr.u[3]=packbf_t(f1.z,f1.w);
    *(short8*)(xpack + (size_t)X*16) = fr.s8;
  }
}

// ---- fully fused GAT: one block per (s, b), 8 waves, all 8 heads in-block ----
// Includes the layer-2 ego-row softmax + log_softmax; mean over S via atomicAdd.
__global__ __launch_bounds__(512,4) void gat_fused(
    const char* __restrict__ xpack, const char* __restrict__ w1pack,
    const float* __restrict__ a_src1, const float* __restrict__ a_dst1,
    const float* __restrict__ b1, const float* __restrict__ w2,
    const float* __restrict__ a_src2, const float* __restrict__ a_dst2,
    const float* __restrict__ b2,
    const uint32_t* __restrict__ mask_ws, float* __restrict__ out)
{
  __shared__ __align__(16) char smem[L_SIZE];
  char*     hf    = smem + L_HF;
  uint32_t* hf_u  = (uint32_t*)(smem + L_HF);
  float*    src_l = (float*)(smem + L_SRC);
  float*    dst_l = (float*)(smem + L_DST);
  uint32_t* mask_l= (uint32_t*)(smem + L_MASK);
  const uint4* mask4 = (const uint4*)(smem + L_MASK);
  float2*   h2p   = (float2*)(smem + L_H2P);

  const int t    = threadIdx.x;
  const int blk  = blockIdx.x;
  const int s    = blk >> 7;
  const int bb   = blk & 127;
  const int lane = t & 63, w = t >> 6;
  const int of = lane & 15, kg = lane >> 4;

  // stage pre-packed mask rows (512 u32, coalesced)
  mask_l[t] = mask_ws[(size_t)bb*512 + t];

  // ---------- Phase 0a: A-frags, 4 coalesced 16B loads from pre-packed xpack ----------
  const char* xsrc = xpack + ((size_t)((bb*8 + w)*4)*64 + lane)*16;
  short8 af[4];
  #pragma unroll
  for (int ks=0; ks<4; ++ks) af[ks] = *(const short8*)(xsrc + ks*1024);

  // ---------- Phase 0b: stage pre-packed W1 B-frags (32 KB, coalesced copy) ----------
  {
    const char* wsrc = w1pack + ((size_t)s << 15);
    #pragma unroll
    for (int r=0; r<4; ++r){
      const int L = t + r*512;
      *(short8*)(hf + (size_t)L*16) = *(const short8*)(wsrc + (size_t)L*16);
    }
  }
  __syncthreads();

  // ---------- Phase 1: h = x0 @ W1 via MFMA (8 heads) ----------
  floatx4 acc[8];
  #pragma unroll
  for (int ct=0; ct<8; ++ct) acc[ct]=(floatx4){0.f,0.f,0.f,0.f};
  #pragma unroll
  for (int ct=0; ct<8; ++ct)
    #pragma unroll
    for (int ks=0; ks<4; ++ks){
      short8 bfr = *(const short8*)(hf + ((ct*4+ks)*64 + lane)*16);
      acc[ct] = __builtin_amdgcn_mfma_f32_16x16x32_bf16(af[ks], bfr, acc[ct], 0,0,0);
    }
  __syncthreads();                            // all W1-frag reads done before h overwrite

  // epilogue: tanh -> att partials (x log2e) via DPP row-reduce; h -> LDS in B-frag order
  const int ks_h = w>>1, kgp = (w&1)*2 + (kg>>1), vv = (kg&1)*2;
  #pragma unroll
  for (int ct=0; ct<8; ++ct){
    float asv = a_src1[s*128 + ct*16 + of] * LOG2E;
    float adv = a_dst1[s*128 + ct*16 + of] * LOG2E;
    float ps[4], pd[4];
    #pragma unroll
    for (int r=0; r<4; ++r){
      float th = fast_tanh(acc[ct][r]);
      ps[r] = red16(th*asv); pd[r] = red16(th*adv);
    }
    if (of==0){
      #pragma unroll
      for (int r=0; r<4; ++r){
        int i = w*16 + kg*4 + r;
        src_l[ct*128+i]=ps[r]; dst_l[ct*128+i]=pd[r];
      }
    }
    uint32_t p0 = packbf(acc[ct][0], acc[ct][1]);
    uint32_t p1 = packbf(acc[ct][2], acc[ct][3]);
    uint32_t* dsth = hf_u + ((ct*4+ks_h)*64 + kgp*16 + of)*4 + vv;
    *(uint2*)dsth = make_uint2(p0, p1);
  }
  __syncthreads();

  // ---------- Phase 2: softmax(lrelu(src+dst)) @ h, fused elu + W2 dot ----------
  // One wave per head; paired row-tiles; z via MFMA-with-ones.
  const int hd = w;                           // head for this wave
  float b1v  = b1[of];
  float w2c0 = w2[s*256 + (hd*16+of)*2 + 0];
  float w2c1 = w2[s*256 + (hd*16+of)*2 + 1];
  F8 onesf;                                   // bf16 1.0 x8
  onesf.u[0]=0x3F803F80u; onesf.u[1]=0x3F803F80u;
  onesf.u[2]=0x3F803F80u; onesf.u[3]=0x3F803F80u;

  #pragma unroll 2
  for (int pp=0; pp<4; ++pp){
    const int rt0 = pp*2, rt1 = rt0 + 1;
    const int im0 = rt0*16 + of, im1 = rt1*16 + of;
    float srcv0 = src_l[hd*128 + im0];
    float srcv1 = src_l[hd*128 + im1];
    uint4 mrow0 = mask4[im0];
    uint4 mrow1 = mask4[im1];
    floatx4 acc20 = (floatx4){0.f,0.f,0.f,0.f};
    floatx4 acc21 = (floatx4){0.f,0.f,0.f,0.f};
    floatx4 accz0 = (floatx4){0.f,0.f,0.f,0.f};
    floatx4 accz1 = (floatx4){0.f,0.f,0.f,0.f};
    #pragma unroll
    for (int ks=0; ks<4; ++ks){
      const float* dp = dst_l + hd*128 + ks*32 + kg*8;
      float4 d0 = *(const float4*)dp, d1 = *(const float4*)(dp+4);
      short8 hbk = *(const short8*)(hf + ((hd*4+ks)*64 + lane)*16);
      uint32_t mw0 = (ks==0)?mrow0.x:(ks==1)?mrow0.y:(ks==2)?mrow0.z:mrow0.w;
      uint32_t mw1 = (ks==0)?mrow1.x:(ks==1)?mrow1.y:(ks==2)?mrow1.z:mrow1.w;
      uint32_t mb0 = mw0 >> (kg*8);
      uint32_t mb1 = mw1 >> (kg*8);
      float dj[8] = {d0.x,d0.y,d0.z,d0.w,d1.x,d1.y,d1.z,d1.w};
      F8 fr0, fr1;
      #pragma unroll
      for (int jp=0; jp<4; ++jp){
        const int j0 = 2*jp, j1 = 2*jp+1;
        float ta0 = srcv0 + dj[j0], ta1 = srcv0 + dj[j1];
        float tb0 = srcv1 + dj[j0], tb1 = srcv1 + dj[j1];
        float la0 = fmaxf(ta0, 0.2f*ta0), la1 = fmaxf(ta1, 0.2f*ta1);
        float lb0 = fmaxf(tb0, 0.2f*tb0), lb1 = fmaxf(tb1, 0.2f*tb1);
        float ea0 = mexp2(la0, mb0, j0), ea1 = mexp2(la1, mb0, j1);
        float eb0 = mexp2(lb0, mb1, j0), eb1 = mexp2(lb1, mb1, j1);
        fr0.u[jp] = packbf_t(ea0, ea1);
        fr1.u[jp] = packbf_t(eb0, eb1);
      }
      acc20 = __builtin_amdgcn_mfma_f32_16x16x32_bf16(fr0.s8, hbk,      acc20, 0,0,0);
      accz0 = __builtin_amdgcn_mfma_f32_16x16x32_bf16(fr0.s8, onesf.s8, accz0, 0,0,0);
      acc21 = __builtin_amdgcn_mfma_f32_16x16x32_bf16(fr1.s8, hbk,      acc21, 0,0,0);
      accz1 = __builtin_amdgcn_mfma_f32_16x16x32_bf16(fr1.s8, onesf.s8, accz1, 0,0,0);
    }
    #pragma unroll
    for (int pr=0; pr<2; ++pr){
      const int rt = pr ? rt1 : rt0;
      floatx4 a2 = pr ? acc21 : acc20;
      floatx4 az = pr ? accz1 : accz0;
      float pc0[4], pc1[4];
      #pragma unroll
      for (int r=0; r<4; ++r){
        float zi = __builtin_amdgcn_rcpf(az[r]);    // z for row kg*4+r, in-slot
        float o  = fmaf(a2[r], zi, b1v);
        float oe = (o>0.f) ? o : (__expf(o)-1.f);   // elu
        pc0[r] = red16(oe*w2c0);
        pc1[r] = red16(oe*w2c1);
      }
      if (of==0){
        #pragma unroll
        for (int r=0; r<4; ++r){
          int i = rt*16 + kg*4 + r;
          h2p[hd*128 + i] = make_float2(pc0[r], pc1[r]);
        }
      }
    }
  }
  __syncthreads();

  // ---------- in-block layer-2 tail: ego-row softmax + log_softmax ----------
  // hv[j][c] = sum over 8 heads of h2p; one wave handles all 128 nodes (2 j per lane).
  if (w == 0){
    float hv[2][2];
    #pragma unroll
    for (int jj=0; jj<2; ++jj){
      const int j = lane + jj*64;
      float s0 = 0.f, s1 = 0.f;
      #pragma unroll
      for (int h2i=0; h2i<8; ++h2i){
        float2 p = h2p[h2i*128 + j];
        s0 += p.x; s1 += p.y;
      }
      hv[jj][0] = s0; hv[jj][1] = s1;
    }
    const float as0 = a_src2[s*2+0], as1 = a_src2[s*2+1];
    const float ad0 = a_dst2[s*2+0], ad1 = a_dst2[s*2+1];
    float ps1v = 0.f, pd[2];
    #pragma unroll
    for (int jj=0; jj<2; ++jj){
      float th0 = fast_tanh(hv[jj][0]);
      float th1 = fast_tanh(hv[jj][1]);
      float psj = th0*as0 + th1*as1;
      pd[jj]    = th0*ad0 + th1*ad1;
      if (jj==1) ps1v = psj;
    }
    const float srcE = __shfl(ps1v, 63);       // ego node j=127
    const uint32_t mwA = mask_l[127*4 + (lane>>5)];
    const uint32_t mwB = mask_l[127*4 + 2 + (lane>>5)];
    const int bitpos = lane & 31;
    float v[2];
    #pragma unroll
    for (int jj=0; jj<2; ++jj){
      float t0 = srcE + pd[jj];
      float lg = fmaxf(t0, 0.2f*t0);
      uint32_t mb = jj ? mwB : mwA;
      v[jj] = ((mb >> bitpos) & 1u) ? lg : -1e9f;
    }
    float M = fmaxf(v[0], v[1]);
    #pragma unroll
    for (int off=32; off>=1; off>>=1) M = fmaxf(M, __shfl_xor(M, off));
    float e0 = __expf(v[0]-M), e1 = __expf(v[1]-M);
    float Z  = e0 + e1;
    float S0 = e0*hv[0][0] + e1*hv[1][0];
    float S1 = e0*hv[0][1] + e1*hv[1][1];
    #pragma unroll
    for (int off=32; off>=1; off>>=1){
      Z  += __shfl_xor(Z,  off);
      S0 += __shfl_xor(S0, off);
      S1 += __shfl_xor(S1, off);
    }
    if (lane == 0){
      float o0 = S0/Z + b2[0];
      float o1 = S1/Z + b2[1];
      float mm = fmaxf(o0,o1);
      float lse = mm + logf(__expf(o0-mm)+__expf(o1-mm));
      atomicAdd(out + bb*2 + 0, 0.25f*(o0 - lse));
      atomicAdd(out + bb*2 + 1, 0.25f*(o1 - lse));
    }
  }
}

extern "C" void kernel_launch(void* const* d_in, const int* in_sizes, int n_in,
                              void* d_out, int out_size, void* d_ws, size_t ws_size,
                              hipStream_t stream) {
  const float* x      = (const float*)d_in[0];
  const float* emb    = (const float*)d_in[1];
  const int*   adj    = (const int*)d_in[2];
  const float* w1     = (const float*)d_in[3];
  const float* a_src1 = (const float*)d_in[4];
  const float* a_dst1 = (const float*)d_in[5];
  const float* b1     = (const float*)d_in[6];
  const float* w2     = (const float*)d_in[7];
  const float* a_src2 = (const float*)d_in[8];
  const float* a_dst2 = (const float*)d_in[9];
  const float* b2     = (const float*)d_in[10];

  uint32_t* mask_ws = (uint32_t*)((char*)d_ws + WS_MASK);
  char*     w1pack  = (char*)d_ws + WS_W1P;
  char*     xpack   = (char*)d_ws + WS_XP;

  prep<<<dim3(512), dim3(256), 0, stream>>>(adj, x, emb, w1, mask_ws, w1pack,
                                            xpack, (float*)d_out);
  gat_fused<<<dim3(512), dim3(512), 0, stream>>>(xpack, w1pack, a_src1, a_dst1, b1,
                                                 w2, a_src2, a_dst2, b2,
                                                 mask_ws, (float*)d_out);
}